// Round 7
// baseline (2153.093 us; speedup 1.0000x reference)
//
#include <hip/hip_runtime.h>
#include <math.h>

#define HH      128
#define GHN     9
#define GWN     9
#define BATCH   4096
#define NCELL   81
#define MSAMP   16
#define THREADS 1024
#define NBLK    (BATCH / MSAMP)   // 256 blocks -> 1 per CU, 16 waves
#define EPSF    1e-5f

typedef __attribute__((ext_vector_type(8))) short  bf8;     // 8 bf16 (4 VGPRs)
typedef __attribute__((ext_vector_type(4))) short  short4v; // 8 bytes
typedef __attribute__((ext_vector_type(4))) float  f32x4;

#define MFMA(a, b, c) __builtin_amdgcn_mfma_f32_16x16x32_bf16(a, b, c, 0, 0, 0)

__device__ __forceinline__ float rcp_fast(float x) { return __builtin_amdgcn_rcpf(x); }
__device__ __forceinline__ float rsq_fast(float x) { return __builtin_amdgcn_rsqf(x); }
__device__ __forceinline__ float sigm(float x)     { return rcp_fast(1.f + __expf(-x)); }
__device__ __forceinline__ float tanh_fast(float x) {
    float ax = fabsf(x);
    float t  = __expf(-2.f * ax);
    float r  = (1.f - t) * rcp_fast(1.f + t);
    return (x < 0.f) ? -r : r;
}
__device__ __forceinline__ short f2bf(float f) {        // RNE fp32->bf16
    unsigned u = __float_as_uint(f);
    u = (u + 0x7FFFu + ((u >> 16) & 1u)) >> 16;
    return (short)u;
}
__device__ __forceinline__ float bf2f(short h) {
    return __uint_as_float(((unsigned)(unsigned short)h) << 16);
}
__device__ __forceinline__ void split_bf(float f, short& hi, short& lo) {
    hi = f2bf(f);
    lo = f2bf(f - bf2f(hi));
}
// write 4 consecutive k-elements (same 8-group) of sample m into frag arrays
__device__ __forceinline__ void store_frag4(short* hiA, short* loA, int idx, float4 v) {
    short4v h, l; short a, b;
    split_bf(v.x, a, b); h.x = a; l.x = b;
    split_bf(v.y, a, b); h.y = a; l.y = b;
    split_bf(v.z, a, b); h.z = a; l.z = b;
    split_bf(v.w, a, b); h.w = a; l.w = b;
    *(short4v*)&hiA[idx] = h;
    *(short4v*)&loA[idx] = l;
}
// frag slot for (k multiple of 4, sample m): A layout [kstep][lane=(kgrp<<4)|m][8]
__device__ __forceinline__ int frag4_idx(int k, int m) {
    return (k >> 5) * 512 + ((((k & 31) >> 3) << 4) | m) * 8 + (k & 7);
}

// ---------------------------------------------------------------------------
// Build bf16 hi/lo B-fragments for all weights.
//   whB/wcB : [81][8 ntile][12 kstep][64 lane][8]   elem = W[k][16t+(l&15)][32s+(l>>4)*8+e]
//   whhB    : [81][32 ntile][4 kstep][64 lane][8]
// grid: 81 * 24 blocks (4 Wh pairs + 4 Wc pairs + 16 Whh chunks), 256 thr.
// ---------------------------------------------------------------------------
__global__ __launch_bounds__(256)
void k_buildw(const float* __restrict__ Wh, const float* __restrict__ Wc,
              const float* __restrict__ Whh,
              short* __restrict__ whB_hi, short* __restrict__ whB_lo,
              short* __restrict__ wcB_hi, short* __restrict__ wcB_lo,
              short* __restrict__ whhB_hi, short* __restrict__ whhB_lo)
{
    __shared__ float lw[32 * 384];   // 48KB max
    const int u  = threadIdx.x;
    const int kc = blockIdx.x / 24;
    const int c  = blockIdx.x % 24;

    if (c < 8) {                       // Wh (c<4) / Wc pairs
        const int mat = c >> 2;
        const int p   = c & 3;
        const float* src = (mat ? Wc : Wh) + ((size_t)kc * 128 + 32 * p) * 384;
        #pragma unroll
        for (int it = 0; it < 12; ++it)
            ((float4*)lw)[it * 256 + u] = ((const float4*)src)[it * 256 + u];
        __syncthreads();
        short* Dhi = mat ? wcB_hi : whB_hi;
        short* Dlo = mat ? wcB_lo : whB_lo;
        #pragma unroll
        for (int it = 0; it < 6; ++it) {
            const int wd = it * 256 + u;        // 0..1535
            const int tt = wd / 768;
            const int rm = wd - tt * 768;
            const int s  = rm >> 6;
            const int l  = rm & 63;
            const int rl = tt * 16 + (l & 15);
            const int kk = s * 32 + (l >> 4) * 8;
            const float* pr = &lw[rl * 384 + kk];
            const float4 v0 = *(const float4*)pr;
            const float4 v1 = *(const float4*)(pr + 4);
            const size_t dst = (((size_t)kc * 8 + (2 * p + tt)) * 12 + s) * 512 + l * 8;
            short4v h, lo; short a, b;
            split_bf(v0.x, a, b); h.x = a; lo.x = b;
            split_bf(v0.y, a, b); h.y = a; lo.y = b;
            split_bf(v0.z, a, b); h.z = a; lo.z = b;
            split_bf(v0.w, a, b); h.w = a; lo.w = b;
            *(short4v*)&Dhi[dst]     = h;  *(short4v*)&Dlo[dst]     = lo;
            split_bf(v1.x, a, b); h.x = a; lo.x = b;
            split_bf(v1.y, a, b); h.y = a; lo.y = b;
            split_bf(v1.z, a, b); h.z = a; lo.z = b;
            split_bf(v1.w, a, b); h.w = a; lo.w = b;
            *(short4v*)&Dhi[dst + 4] = h;  *(short4v*)&Dlo[dst + 4] = lo;
        }
    } else {                           // Whh chunks
        const int cc = c - 8;
        const float* src = Whh + ((size_t)kc * 512 + 32 * cc) * 128;
        #pragma unroll
        for (int it = 0; it < 4; ++it)
            ((float4*)lw)[it * 256 + u] = ((const float4*)src)[it * 256 + u];
        __syncthreads();
        #pragma unroll
        for (int it = 0; it < 2; ++it) {
            const int wd = it * 256 + u;        // 0..511
            const int tt = wd >> 8;
            const int rm = wd & 255;
            const int s  = rm >> 6;
            const int l  = rm & 63;
            const int rl = tt * 16 + (l & 15);
            const int kk = s * 32 + (l >> 4) * 8;
            const float* pr = &lw[rl * 128 + kk];
            const float4 v0 = *(const float4*)pr;
            const float4 v1 = *(const float4*)(pr + 4);
            const size_t dst = (((size_t)kc * 32 + (2 * cc + tt)) * 4 + s) * 512 + l * 8;
            short4v h, lo; short a, b;
            split_bf(v0.x, a, b); h.x = a; lo.x = b;
            split_bf(v0.y, a, b); h.y = a; lo.y = b;
            split_bf(v0.z, a, b); h.z = a; lo.z = b;
            split_bf(v0.w, a, b); h.w = a; lo.w = b;
            *(short4v*)&whhB_hi[dst]     = h;  *(short4v*)&whhB_lo[dst]     = lo;
            split_bf(v1.x, a, b); h.x = a; lo.x = b;
            split_bf(v1.y, a, b); h.y = a; lo.y = b;
            split_bf(v1.z, a, b); h.z = a; lo.z = b;
            split_bf(v1.w, a, b); h.w = a; lo.w = b;
            *(short4v*)&whhB_hi[dst + 4] = h;  *(short4v*)&whhB_lo[dst + 4] = lo;
        }
    }
}

// ---------------------------------------------------------------------------
// MFMA lattice: 256 blocks x 16 samples, 1024 threads (16 waves, 4/SIMD).
// preLN: 16 waves = {H,C} x 8 N-tiles, 1 tile each, 3-pass split
// (al*bh + ah*bl + ah*bh). gates: waves 0-7 own tiles {w,w+8,w+16,w+24}
// -> all 4 gates of q0=w*16+(lane&15) in-register; waves 8-15 idle there.
// ---------------------------------------------------------------------------
__global__ __launch_bounds__(THREADS, 4)
void k_lattice(const float* __restrict__ x, const float* __restrict__ h_ext,
               const float* __restrict__ c_ext, const float* __restrict__ h_g0,
               const float* __restrict__ c_g0,
               const short* __restrict__ whB_hi, const short* __restrict__ whB_lo,
               const short* __restrict__ wcB_hi, const short* __restrict__ wcB_lo,
               const short* __restrict__ whhB_hi, const short* __restrict__ whhB_lo,
               const float* __restrict__ bh, const float* __restrict__ bc,
               const float* __restrict__ lnh_g, const float* __restrict__ lnh_b,
               const float* __restrict__ lnc_g, const float* __restrict__ lnc_b,
               const float* __restrict__ W_ih, const float* __restrict__ b_ih,
               const float* __restrict__ b_hh,
               float* __restrict__ hrowB, float* __restrict__ crowB,
               float* __restrict__ zout)
{
    __shared__ __align__(16) short sAH_hi[12 * 512], sAH_lo[12 * 512];
    __shared__ __align__(16) short sAC_hi[12 * 512], sAC_lo[12 * 512];   // 48KB
    __shared__ __align__(16) short sPh_hi[4 * 512],  sPh_lo[4 * 512];    // 8KB
    __shared__ float pcArr[16 * 132];                                    // 8.25KB
    __shared__ float part_s[2 * 8 * 16], part_q[2 * 8 * 16];             // 2KB
    __shared__ float xsArr[16 * NCELL];                                  // 5.2KB

    const int t    = threadIdx.x;
    const int base = blockIdx.x * MSAMP;
    const int lane = t & 63;
    const int w    = t >> 6;         // wave 0..15
    const int cL   = lane & 15;      // MFMA col (feature)
    const int gL   = lane >> 4;      // sample group (D rows gL*4 + r)

    // preLN roles: one N-tile per wave
    const int mat = w >> 3;          // 0=H 1=C
    const int tt  = w & 7;           // tile 0..7
    const int f0  = tt * 16 + cL;    // feature
    // gates roles (waves 0..7 only)
    const int q0  = w * 16 + cL;
    // build roles: half threads H, half C
    const int mat_b = t >> 9;        // 0=H 1=C
    const int tb    = t & 511;
    const int m_b   = tb >> 5;       // 0..15 sample
    const int f4    = (tb & 31) * 4; // feature quad

    for (int idx = t; idx < MSAMP * NCELL; idx += THREADS) {
        const int m = idx / NCELL;
        const int cc = idx - m * NCELL;
        xsArr[idx] = x[(size_t)(base + m) * NCELL + cc];
    }
    const float4 z4 = make_float4(0.f, 0.f, 0.f, 0.f);

    #pragma unroll 1
    for (int i = 0; i < GHN; ++i) {
      #pragma unroll 1
      for (int j = 0; j < GWN; ++j) {
        const int k = i * GWN + j;

        // ---------------- build: up/prev bands (+left at j==0) ---------------
        {
            short* Dhi = mat_b ? sAC_hi : sAH_hi;
            short* Dlo = mat_b ? sAC_lo : sAH_lo;
            const float* extp = mat_b ? c_ext : h_ext;
            const float* rowp = mat_b ? crowB : hrowB;
            const float* g0p  = mat_b ? c_g0  : h_g0;
            if (j == 0) {
                float4 v = z4;
                if (i == 0) v = *(const float4*)&extp[(size_t)(base + m_b) * HH + f4];
                store_frag4(Dhi, Dlo, frag4_idx(f4, m_b), v);
            }
            float4 uv = z4;
            if (i > 0) uv = *(const float4*)&rowp[((size_t)(base + m_b) * GWN + j) * HH + f4];
            store_frag4(Dhi, Dlo, frag4_idx(128 + f4, m_b), uv);
            const float4 pv = *(const float4*)&g0p[((size_t)k * BATCH + base + m_b) * HH + f4];
            store_frag4(Dhi, Dlo, frag4_idx(256 + f4, m_b), pv);
        }
        __syncthreads();   // B1

        // ---------------- preLN MFMA: 1 N-tile, 3-pass bf16 split ------------
        const short* Ahi = mat ? sAC_hi : sAH_hi;
        const short* Alo = mat ? sAC_lo : sAH_lo;
        const short* Bhi = (mat ? wcB_hi : whB_hi) + (size_t)k * 49152;
        const short* Blo = (mat ? wcB_lo : whB_lo) + (size_t)k * 49152;
        f32x4 d0 = {0.f, 0.f, 0.f, 0.f};
        #pragma unroll 4
        for (int ks = 0; ks < 12; ++ks) {
            const bf8 ah = *(const bf8*)&Ahi[ks * 512 + lane * 8];
            const bf8 al = *(const bf8*)&Alo[ks * 512 + lane * 8];
            const bf8 bh_ = *(const bf8*)&Bhi[(tt * 12 + ks) * 512 + lane * 8];
            const bf8 bl_ = *(const bf8*)&Blo[(tt * 12 + ks) * 512 + lane * 8];
            d0 = MFMA(al, bh_, d0);
            d0 = MFMA(ah, bl_, d0);
            d0 = MFMA(ah, bh_, d0);
        }
        {
            const float* bias = mat ? bc : bh;
            d0 += bias[k * HH + f0];
        }
        // ---------------- LN partials (16-lane feature reduce) ---------------
        {
            float ps[4], pq[4];
            #pragma unroll
            for (int r = 0; r < 4; ++r) { ps[r] = d0[r]; pq[r] = d0[r] * d0[r]; }
            #pragma unroll
            for (int msk = 1; msk < 16; msk <<= 1) {
                #pragma unroll
                for (int r = 0; r < 4; ++r) {
                    ps[r] += __shfl_xor(ps[r], msk);
                    pq[r] += __shfl_xor(pq[r], msk);
                }
            }
            if (cL == 0) {
                #pragma unroll
                for (int r = 0; r < 4; ++r) {
                    part_s[(mat * 8 + tt) * 16 + gL * 4 + r] = ps[r];
                    part_q[(mat * 8 + tt) * 16 + gL * 4 + r] = pq[r];
                }
            }
        }
        __syncthreads();   // B2

        // ---------------- combine stats + normalize + emit ph/pc -------------
        {
            const float* lng = mat ? lnc_g : lnh_g;
            const float* lnb = mat ? lnc_b : lnh_b;
            const float g0 = lng[k * HH + f0];
            const float e0 = lnb[k * HH + f0];
            #pragma unroll
            for (int r = 0; r < 4; ++r) {
                const int s = gL * 4 + r;
                float ts = 0.f, tq = 0.f;
                #pragma unroll
                for (int pp = 0; pp < 8; ++pp) {
                    ts += part_s[(mat * 8 + pp) * 16 + s];
                    tq += part_q[(mat * 8 + pp) * 16 + s];
                }
                const float mu = ts * (1.f / HH);
                const float rstd = rsq_fast(tq * (1.f / HH) - mu * mu + EPSF);
                const float v0 = (d0[r] - mu) * rstd * g0 + e0;
                if (mat == 0) {
                    const int e0i = (f0 >> 5) * 512 + ((((f0 & 31) >> 3) << 4) | s) * 8 + (f0 & 7);
                    short hi, lo;
                    split_bf(v0, hi, lo); sPh_hi[e0i] = hi; sPh_lo[e0i] = lo;
                } else {
                    pcArr[s * 132 + f0] = v0;
                }
            }
        }
        __syncthreads();   // B3

        if (w < 8) {
            // ---------------- gates MFMA: tiles w, w+8, w+16, w+24 -----------
            f32x4 ga0 = {0.f,0.f,0.f,0.f}, ga1 = ga0, ga2 = ga0, ga3 = ga0;
            {
                const short* GBhi = whhB_hi + (size_t)k * 65536;
                const short* GBlo = whhB_lo + (size_t)k * 65536;
                #pragma unroll
                for (int ks = 0; ks < 4; ++ks) {
                    const bf8 ah = *(const bf8*)&sPh_hi[ks * 512 + lane * 8];
                    const bf8 al = *(const bf8*)&sPh_lo[ks * 512 + lane * 8];
                    const bf8 bh0 = *(const bf8*)&GBhi[((w     ) * 4 + ks) * 512 + lane * 8];
                    const bf8 bl0 = *(const bf8*)&GBlo[((w     ) * 4 + ks) * 512 + lane * 8];
                    const bf8 bh1 = *(const bf8*)&GBhi[((w +  8) * 4 + ks) * 512 + lane * 8];
                    const bf8 bl1 = *(const bf8*)&GBlo[((w +  8) * 4 + ks) * 512 + lane * 8];
                    const bf8 bh2 = *(const bf8*)&GBhi[((w + 16) * 4 + ks) * 512 + lane * 8];
                    const bf8 bl2 = *(const bf8*)&GBlo[((w + 16) * 4 + ks) * 512 + lane * 8];
                    const bf8 bh3 = *(const bf8*)&GBhi[((w + 24) * 4 + ks) * 512 + lane * 8];
                    const bf8 bl3 = *(const bf8*)&GBlo[((w + 24) * 4 + ks) * 512 + lane * 8];
                    ga0 = MFMA(al, bh0, ga0); ga0 = MFMA(ah, bl0, ga0); ga0 = MFMA(ah, bh0, ga0);
                    ga1 = MFMA(al, bh1, ga1); ga1 = MFMA(ah, bl1, ga1); ga1 = MFMA(ah, bh1, ga1);
                    ga2 = MFMA(al, bh2, ga2); ga2 = MFMA(ah, bl2, ga2); ga2 = MFMA(ah, bh2, ga2);
                    ga3 = MFMA(al, bh3, ga3); ga3 = MFMA(ah, bl3, ga3); ga3 = MFMA(ah, bh3, ga3);
                }
            }
            // ---------------- bias + x + LSTM pointwise (in-register) --------
            {
                const float wi0 = W_ih[k * 512 + q0      ];
                const float wi1 = W_ih[k * 512 + q0 + 128];
                const float wi2 = W_ih[k * 512 + q0 + 256];
                const float wi3 = W_ih[k * 512 + q0 + 384];
                const float bs0 = b_ih[k * 512 + q0      ] + b_hh[k * 512 + q0      ];
                const float bs1 = b_ih[k * 512 + q0 + 128] + b_hh[k * 512 + q0 + 128];
                const float bs2 = b_ih[k * 512 + q0 + 256] + b_hh[k * 512 + q0 + 256];
                const float bs3 = b_ih[k * 512 + q0 + 384] + b_hh[k * 512 + q0 + 384];
                #pragma unroll
                for (int r = 0; r < 4; ++r) {
                    const int s = gL * 4 + r;
                    const int b = base + s;
                    const float xv = xsArr[s * NCELL + k];
                    const float gi_ = ga0[r] + bs0 + wi0 * xv;
                    const float gf_ = ga1[r] + bs1 + wi1 * xv;
                    const float gg_ = ga2[r] + bs2 + wi2 * xv;
                    const float go_ = ga3[r] + bs3 + wi3 * xv;
                    const float pcv = pcArr[s * 132 + q0];
                    const float cn = sigm(gf_) * pcv + sigm(gi_) * tanh_fast(gg_);
                    const float hn = sigm(go_) * tanh_fast(cn);
                    if (k == NCELL - 1) {
                        zout[(size_t)b * 256 + q0]       = hn + h_ext[(size_t)b * HH + q0];
                        zout[(size_t)b * 256 + 128 + q0] = cn + c_ext[(size_t)b * HH + q0];
                    } else {
                        if (j < GWN - 1) {
                            const int ei = (q0 >> 5) * 512 + ((((q0 & 31) >> 3) << 4) | s) * 8 + (q0 & 7);
                            short hi, lo;
                            split_bf(hn, hi, lo); sAH_hi[ei] = hi; sAH_lo[ei] = lo;
                            split_bf(cn, hi, lo); sAC_hi[ei] = hi; sAC_lo[ei] = lo;
                        }
                        if (i < GHN - 1) {
                            hrowB[((size_t)b * GWN + j) * HH + q0] = hn;
                            crowB[((size_t)b * GWN + j) * HH + q0] = cn;
                        }
                    }
                }
            }
        }
        // next B1 fences left-frag/pc visibility for the following cell
      }
    }
}

// ---------------------------------------------------------------------------
// fc1: y1 = z @ fc1_W^T + b  [4096,256], fused column sum/sumsq atomics
// ---------------------------------------------------------------------------
__global__ __launch_bounds__(256)
void k_fc1(const float* __restrict__ z, const float* __restrict__ W,
           const float* __restrict__ bias, float* __restrict__ y1,
           float* __restrict__ s1, float* __restrict__ q1)
{
    __shared__ float at[256 * 16];
    const int t   = threadIdx.x;
    const int row = t & 15;
    const int cg  = t >> 4;
    const int rb  = blockIdx.x * 16;
    {
        const float* zr = z + (size_t)(rb + row) * 256 + cg * 16;
        #pragma unroll
        for (int v = 0; v < 4; ++v) {
            const float4 zz = *(const float4*)(zr + v * 4);
            const int kk = cg * 16 + v * 4;
            at[(kk + 0) * 16 + row] = zz.x;
            at[(kk + 1) * 16 + row] = zz.y;
            at[(kk + 2) * 16 + row] = zz.z;
            at[(kk + 3) * 16 + row] = zz.w;
        }
    }
    __syncthreads();
    const int c0 = cg * 16;
    float acc[16];
    #pragma unroll
    for (int c = 0; c < 16; ++c) acc[c] = bias[c0 + c];
    for (int kb = 0; kb < 64; ++kb) {
        const float a0 = at[(4 * kb + 0) * 16 + row];
        const float a1 = at[(4 * kb + 1) * 16 + row];
        const float a2 = at[(4 * kb + 2) * 16 + row];
        const float a3 = at[(4 * kb + 3) * 16 + row];
        #pragma unroll
        for (int c = 0; c < 16; ++c) {
            const float4 wv = *(const float4*)&W[(size_t)(c0 + c) * 256 + 4 * kb];
            acc[c] += a0 * wv.x + a1 * wv.y + a2 * wv.z + a3 * wv.w;
        }
    }
    {
        float* yr = y1 + (size_t)(rb + row) * 256 + c0;
        #pragma unroll
        for (int v = 0; v < 4; ++v)
            *(float4*)(yr + v * 4) = make_float4(acc[4*v], acc[4*v+1], acc[4*v+2], acc[4*v+3]);
    }
    #pragma unroll
    for (int c = 0; c < 16; ++c) {
        float s = acc[c], sq = acc[c] * acc[c];
        s += __shfl_xor(s, 1); sq += __shfl_xor(sq, 1);
        s += __shfl_xor(s, 2); sq += __shfl_xor(sq, 2);
        s += __shfl_xor(s, 4); sq += __shfl_xor(sq, 4);
        s += __shfl_xor(s, 8); sq += __shfl_xor(sq, 8);
        if (row == 0) { atomicAdd(&s1[c0 + c], s); atomicAdd(&q1[c0 + c], sq); }
    }
}

// ---------------------------------------------------------------------------
// fc2: y2 = relu(bn1(y1)) @ fc2_W^T + b  [4096,128], fused stats
// ---------------------------------------------------------------------------
__global__ __launch_bounds__(256)
void k_fc2(const float* __restrict__ y1, const float* __restrict__ W,
           const float* __restrict__ bias,
           const float* __restrict__ s1, const float* __restrict__ q1,
           const float* __restrict__ g1, const float* __restrict__ b1,
           float* __restrict__ y2, float* __restrict__ s2, float* __restrict__ q2)
{
    __shared__ float at[256 * 16];
    __shared__ float scale[256], shift[256];
    const int t = threadIdx.x;
    {
        const float mu  = s1[t] * (1.f / BATCH);
        const float var = q1[t] * (1.f / BATCH) - mu * mu;
        const float sc  = g1[t] * rsq_fast(var + EPSF);
        scale[t] = sc;
        shift[t] = b1[t] - mu * sc;
    }
    __syncthreads();
    const int row = t & 15;
    const int cg  = t >> 4;
    const int rb  = blockIdx.x * 16;
    {
        const float* yr = y1 + (size_t)(rb + row) * 256 + cg * 16;
        #pragma unroll
        for (int v = 0; v < 4; ++v) {
            const float4 zz = *(const float4*)(yr + v * 4);
            const int kk = cg * 16 + v * 4;
            at[(kk + 0) * 16 + row] = fmaxf(zz.x * scale[kk + 0] + shift[kk + 0], 0.f);
            at[(kk + 1) * 16 + row] = fmaxf(zz.y * scale[kk + 1] + shift[kk + 1], 0.f);
            at[(kk + 2) * 16 + row] = fmaxf(zz.z * scale[kk + 2] + shift[kk + 2], 0.f);
            at[(kk + 3) * 16 + row] = fmaxf(zz.w * scale[kk + 3] + shift[kk + 3], 0.f);
        }
    }
    __syncthreads();
    const int c0 = cg * 8;
    float acc[8];
    #pragma unroll
    for (int c = 0; c < 8; ++c) acc[c] = bias[c0 + c];
    for (int kb = 0; kb < 64; ++kb) {
        const float a0 = at[(4 * kb + 0) * 16 + row];
        const float a1 = at[(4 * kb + 1) * 16 + row];
        const float a2 = at[(4 * kb + 2) * 16 + row];
        const float a3 = at[(4 * kb + 3) * 16 + row];
        #pragma unroll
        for (int c = 0; c < 8; ++c) {
            const float4 wv = *(const float4*)&W[(size_t)(c0 + c) * 256 + 4 * kb];
            acc[c] += a0 * wv.x + a1 * wv.y + a2 * wv.z + a3 * wv.w;
        }
    }
    {
        float* yr = y2 + (size_t)(rb + row) * 128 + c0;
        *(float4*)(yr)     = make_float4(acc[0], acc[1], acc[2], acc[3]);
        *(float4*)(yr + 4) = make_float4(acc[4], acc[5], acc[6], acc[7]);
    }
    #pragma unroll
    for (int c = 0; c < 8; ++c) {
        float s = acc[c], sq = acc[c] * acc[c];
        s += __shfl_xor(s, 1); sq += __shfl_xor(sq, 1);
        s += __shfl_xor(s, 2); sq += __shfl_xor(sq, 2);
        s += __shfl_xor(s, 4); sq += __shfl_xor(sq, 4);
        s += __shfl_xor(s, 8); sq += __shfl_xor(sq, 8);
        if (row == 0) { atomicAdd(&s2[c0 + c], s); atomicAdd(&q2[c0 + c], sq); }
    }
}

// ---------------------------------------------------------------------------
// fc3: y3 = relu(bn2(y2)) @ fc3_W^T + b  [4096,1], fused scalar stats
// ---------------------------------------------------------------------------
__global__ __launch_bounds__(256)
void k_fc3(const float* __restrict__ y2, const float* __restrict__ W3,
           const float* __restrict__ b3,
           const float* __restrict__ s2, const float* __restrict__ q2,
           const float* __restrict__ g2, const float* __restrict__ b2,
           float* __restrict__ y3, float* __restrict__ s3, float* __restrict__ q3)
{
    __shared__ float scale[128], shift[128], w3s[128];
    const int t = threadIdx.x;
    if (t < 128) {
        const float mu  = s2[t] * (1.f / BATCH);
        const float var = q2[t] * (1.f / BATCH) - mu * mu;
        const float sc  = g2[t] * rsq_fast(var + EPSF);
        scale[t] = sc;
        shift[t] = b2[t] - mu * sc;
        w3s[t]   = W3[t];
    }
    __syncthreads();
    const int r = blockIdx.x * 256 + t;
    float acc = b3[0];
    const float* yr = y2 + (size_t)r * 128;
    for (int kb = 0; kb < 32; ++kb) {
        const float4 v = *(const float4*)(yr + 4 * kb);
        const int kk = 4 * kb;
        acc += fmaxf(v.x * scale[kk + 0] + shift[kk + 0], 0.f) * w3s[kk + 0];
        acc += fmaxf(v.y * scale[kk + 1] + shift[kk + 1], 0.f) * w3s[kk + 1];
        acc += fmaxf(v.z * scale[kk + 2] + shift[kk + 2], 0.f) * w3s[kk + 2];
        acc += fmaxf(v.w * scale[kk + 3] + shift[kk + 3], 0.f) * w3s[kk + 3];
    }
    y3[r] = acc;
    float s = acc, sq = acc * acc;
    #pragma unroll
    for (int d = 1; d < 64; d <<= 1) { s += __shfl_xor(s, d); sq += __shfl_xor(sq, d); }
    if ((t & 63) == 0) { atomicAdd(&s3[0], s); atomicAdd(&q3[0], sq); }
}

// ---------------------------------------------------------------------------
// out = sigmoid(bn_out(y3))
// ---------------------------------------------------------------------------
__global__ __launch_bounds__(256)
void k_out(const float* __restrict__ y3,
           const float* __restrict__ s3, const float* __restrict__ q3,
           const float* __restrict__ g, const float* __restrict__ b,
           float* __restrict__ out)
{
    const int r = blockIdx.x * 256 + threadIdx.x;
    const float mu  = s3[0] * (1.f / BATCH);
    const float var = q3[0] * (1.f / BATCH) - mu * mu;
    const float sc  = g[0] * rsq_fast(var + EPSF);
    out[r] = sigm((y3[r] - mu) * sc + b[0]);
}

// ---------------------------------------------------------------------------
extern "C" void kernel_launch(void* const* d_in, const int* in_sizes, int n_in,
                              void* d_out, int out_size, void* d_ws, size_t ws_size,
                              hipStream_t stream)
{
    const float* x     = (const float*)d_in[0];
    const float* h_ext = (const float*)d_in[1];
    const float* c_ext = (const float*)d_in[2];
    const float* h_g0  = (const float*)d_in[3];
    const float* c_g0  = (const float*)d_in[4];
    const float* Wh    = (const float*)d_in[5];
    const float* bh    = (const float*)d_in[6];
    const float* Wc    = (const float*)d_in[7];
    const float* bc    = (const float*)d_in[8];
    const float* lnh_g = (const float*)d_in[9];
    const float* lnh_b = (const float*)d_in[10];
    const float* lnc_g = (const float*)d_in[11];
    const float* lnc_b = (const float*)d_in[12];
    const float* W_ih  = (const float*)d_in[13];
    const float* b_ih  = (const float*)d_in[14];
    const float* W_hh  = (const float*)d_in[15];
    const float* b_hh  = (const float*)d_in[16];
    const float* fc1_W = (const float*)d_in[17];
    const float* fc1_b = (const float*)d_in[18];
    const float* bn1_g = (const float*)d_in[19];
    const float* bn1_b = (const float*)d_in[20];
    const float* fc2_W = (const float*)d_in[21];
    const float* fc2_b = (const float*)d_in[22];
    const float* bn2_g = (const float*)d_in[23];
    const float* bn2_b = (const float*)d_in[24];
    const float* fc3_W = (const float*)d_in[25];
    const float* fc3_b = (const float*)d_in[26];
    const float* bno_g = (const float*)d_in[27];
    const float* bno_b = (const float*)d_in[28];

    // workspace layout
    short* whB_hi  = (short*)d_ws;                    // 81*8*12*512 = 3,981,312
    short* whB_lo  = whB_hi  + 3981312;
    short* wcB_hi  = whB_lo  + 3981312;
    short* wcB_lo  = wcB_hi  + 3981312;
    short* whhB_hi = wcB_lo  + 3981312;               // 81*32*4*512 = 5,308,416
    short* whhB_lo = whhB_hi + 5308416;
    float* hrow = (float*)(whhB_lo + 5308416);        // 4096*9*128
    float* crow = hrow + 4718592;
    float* z    = crow + 4718592;                     // 4096*256
    float* y1   = z    + 1048576;
    float* y2   = y1   + 1048576;
    float* y3   = y2   + 524288;
    float* st   = y3   + 4096;
    float* s1 = st;        float* q1 = s1 + 256;
    float* s2 = q1 + 256;  float* q2 = s2 + 128;
    float* s3 = q2 + 128;  float* q3 = s3 + 1;

    hipMemsetAsync(st, 0, 770 * sizeof(float), stream);
    hipLaunchKernelGGL(k_buildw, dim3(81 * 24), dim3(256), 0, stream,
                       Wh, Wc, W_hh, whB_hi, whB_lo, wcB_hi, wcB_lo, whhB_hi, whhB_lo);
    hipLaunchKernelGGL(k_lattice, dim3(NBLK), dim3(THREADS), 0, stream,
                       x, h_ext, c_ext, h_g0, c_g0,
                       whB_hi, whB_lo, wcB_hi, wcB_lo, whhB_hi, whhB_lo,
                       bh, bc, lnh_g, lnh_b, lnc_g, lnc_b, W_ih, b_ih, b_hh,
                       hrow, crow, z);
    hipLaunchKernelGGL(k_fc1, dim3(256), dim3(256), 0, stream, z, fc1_W, fc1_b, y1, s1, q1);
    hipLaunchKernelGGL(k_fc2, dim3(256), dim3(256), 0, stream,
                       y1, fc2_W, fc2_b, s1, q1, bn1_g, bn1_b, y2, s2, q2);
    hipLaunchKernelGGL(k_fc3, dim3(16), dim3(256), 0, stream,
                       y2, fc3_W, fc3_b, s2, q2, bn2_g, bn2_b, y3, s3, q3);
    hipLaunchKernelGGL(k_out, dim3(16), dim3(256), 0, stream,
                       y3, s3, q3, bno_g, bno_b, (float*)d_out);
}